// Round 5
// baseline (33875.137 us; speedup 1.0000x reference)
//
#include <hip/hip_runtime.h>

// WeightedRGCN on MI355X. Round 5: fp32 inputs AND fp32 outputs (reference
// dtypes are authoritative; R4's inf proved inputs are fp32, R1/R3's
// error==max|ref| proved output buffer is fp32 — bf16 writes left the fp32
// buffer as bounded garbage).
// Algorithm: atomic-scatter mean-aggregation + LDS-staged row GEMMs,
// fp32 accumulation, bf16 staging of B tiles only (error ~2e-3 << 0.214).
//
// ws layout (floats), total 25.9M floats = 103.6 MB:
//   user phase: [0 .. 12.8M) aggU   [12.8M .. 25.6M) uacc
//   post phase: [0 .. 25.6M) aggP   (reuses both, after user_final)
//   [25.6M .. +100K) cntU   [25.7M .. +200K) cntP

#define N_USER 100000
#define N_POST 200000
#define DD 128

__device__ __forceinline__ unsigned int pack2_bf16(float lo, float hi) {
    unsigned int ulo, uhi;
    __builtin_memcpy(&ulo, &lo, 4);
    __builtin_memcpy(&uhi, &hi, 4);
    unsigned int rlo = (ulo + 0x7fffu + ((ulo >> 16) & 1u)) >> 16;   // RNE
    unsigned int rhi = (uhi + 0x7fffu + ((uhi >> 16) & 1u)) >> 16;
    return (rlo & 0xffffu) | (rhi << 16);
}
__device__ __forceinline__ float bf16_lo(unsigned int u) {
    unsigned int t = u << 16; float f; __builtin_memcpy(&f, &t, 4); return f;
}
__device__ __forceinline__ float bf16_hi(unsigned int u) {
    unsigned int t = u & 0xffff0000u; float f; __builtin_memcpy(&f, &t, 4); return f;
}

// ---------------------------------------------------------------- scatter ---
// One wave per edge (grid-stride). 512B coalesced fp32 gather, 128 atomics.
__global__ __launch_bounds__(256) void scatter_add_kernel(
        const float* __restrict__ xsrc, const int* __restrict__ src,
        const int* __restrict__ dst, int E,
        float* __restrict__ agg, float* __restrict__ cnt) {
    int lane = threadIdx.x & 63;
    int wave = (blockIdx.x * blockDim.x + threadIdx.x) >> 6;
    int nwaves = (gridDim.x * blockDim.x) >> 6;
    for (int e = wave; e < E; e += nwaves) {
        int s = src[e];
        int d = dst[e];
        float2 v = *reinterpret_cast<const float2*>(xsrc + (size_t)s * DD + lane * 2);
        float* ap = agg + (size_t)d * DD + lane * 2;
        atomicAdd(ap,     v.x);
        atomicAdd(ap + 1, v.y);
        if (lane == 0) atomicAdd(cnt + d, 1.0f);
    }
}

// ------------------------------------------------------------ GEMM pieces ---
// B (fp32 [128][128]) staged in LDS as bf16 column-pairs:
// Bp[k*64+j] = (bf16(B[k][j]), bf16(B[k][j+64])).
__device__ __forceinline__ void stage_B(const float* __restrict__ B,
                                        unsigned int* Bp, int tid) {
    for (int i = tid; i < 128 * 64; i += 512) {
        int k = i >> 6, j = i & 63;
        Bp[i] = pack2_bf16(B[k * 128 + j], B[k * 128 + j + 64]);
    }
}

// 4 rows of A (optionally mean-scaled) -> per-wave transposed LDS:
// at[k*4+i] = A[row_i][k] * inv_i  (k-loop broadcast = 1 ds_read_b128)
__device__ __forceinline__ void load_rows(const float* __restrict__ A,
                                          const float* __restrict__ cnt, float scale,
                                          int base, int N, int lane, float* at) {
#pragma unroll
    for (int i = 0; i < 4; ++i) {
        int row = base + i;
        float a0 = 0.f, a1 = 0.f;
        if (row < N) {
            float inv = scale;
            if (cnt) inv = scale / fmaxf(cnt[row], 1.0f);
            a0 = A[(size_t)row * DD + lane] * inv;
            a1 = A[(size_t)row * DD + 64 + lane] * inv;
        }
        at[lane * 4 + i] = a0;
        at[(lane + 64) * 4 + i] = a1;
    }
}

// acc[i][0] += A[row_i][:] . B[:][lane]; acc[i][1] += ... B[:][lane+64]
__device__ __forceinline__ void kloop_acc(const float* at, const unsigned int* Bp,
                                          int lane, float acc[4][2]) {
#pragma unroll
    for (int k = 0; k < 128; ++k) {
        float4 x = *reinterpret_cast<const float4*>(at + k * 4);
        unsigned int u = Bp[k * 64 + lane];
        float b0 = bf16_lo(u), b1 = bf16_hi(u);
        acc[0][0] = fmaf(x.x, b0, acc[0][0]); acc[0][1] = fmaf(x.x, b1, acc[0][1]);
        acc[1][0] = fmaf(x.y, b0, acc[1][0]); acc[1][1] = fmaf(x.y, b1, acc[1][1]);
        acc[2][0] = fmaf(x.z, b0, acc[2][0]); acc[2][1] = fmaf(x.z, b1, acc[2][1]);
        acc[3][0] = fmaf(x.w, b0, acc[3][0]); acc[3][1] = fmaf(x.w, b1, acc[3][1]);
    }
}

// Y (fp32) += scale * mean(A) @ B   (each row owned by exactly one wave)
__global__ __launch_bounds__(512) void row_gemm_acc(
        const float* __restrict__ A, const float* __restrict__ cnt,
        const float* __restrict__ B, float scale, float* __restrict__ Y, int N) {
    __shared__ unsigned int Bp[128 * 64];
    __shared__ __align__(16) float At[8][512];
    stage_B(B, Bp, threadIdx.x);
    __syncthreads();
    int wave = threadIdx.x >> 6, lane = threadIdx.x & 63;
    int base = (blockIdx.x * 8 + wave) * 4;
    float acc[4][2] = {{0.f,0.f},{0.f,0.f},{0.f,0.f},{0.f,0.f}};
    load_rows(A, cnt, scale, base, N, lane, At[wave]);
    kloop_acc(At[wave], Bp, lane, acc);
#pragma unroll
    for (int i = 0; i < 4; ++i) {
        int row = base + i;
        if (row < N) {
            float* y = Y + (size_t)row * DD + lane;
            y[0]  += acc[i][0];
            y[64] += acc[i][1];
        }
    }
}

// out_user = relu(uacc + xU @ (1.75 WrD + 0.7 WrA + 0.3 WrS) + b_comb) [fp32]
__global__ __launch_bounds__(512) void user_final_kernel(
        const float* __restrict__ uacc, const float* __restrict__ xu,
        const float* __restrict__ WrD, const float* __restrict__ WrA,
        const float* __restrict__ WrS, const float* __restrict__ bD,
        const float* __restrict__ bA, const float* __restrict__ bS,
        float* __restrict__ out, int N) {
    __shared__ unsigned int Bp[128 * 64];
    __shared__ __align__(16) float At[8][512];
    for (int i = threadIdx.x; i < 128 * 64; i += 512) {
        int k = i >> 6, j = i & 63;
        float lo = 1.75f * WrD[k*128+j]    + 0.7f * WrA[k*128+j]    + 0.3f * WrS[k*128+j];
        float hi = 1.75f * WrD[k*128+j+64] + 0.7f * WrA[k*128+j+64] + 0.3f * WrS[k*128+j+64];
        Bp[i] = pack2_bf16(lo, hi);
    }
    __syncthreads();
    int wave = threadIdx.x >> 6, lane = threadIdx.x & 63;
    int base = (blockIdx.x * 8 + wave) * 4;
    float acc[4][2] = {{0.f,0.f},{0.f,0.f},{0.f,0.f},{0.f,0.f}};
    load_rows(xu, nullptr, 1.0f, base, N, lane, At[wave]);
    kloop_acc(At[wave], Bp, lane, acc);
    float bc0 = 1.75f*bD[lane]    + 0.7f*bA[lane]    + 0.3f*bS[lane];
    float bc1 = 1.75f*bD[lane+64] + 0.7f*bA[lane+64] + 0.3f*bS[lane+64];
#pragma unroll
    for (int i = 0; i < 4; ++i) {
        int row = base + i;
        if (row < N) {
            const float* u = uacc + (size_t)row * DD + lane;
            out[(size_t)row * DD + lane]      = fmaxf(u[0]  + acc[i][0] + bc0, 0.f);
            out[(size_t)row * DD + lane + 64] = fmaxf(u[64] + acc[i][1] + bc1, 0.f);
        }
    }
}

// out_post = relu(mean(aggP) @ Wl + xP @ Wr + b)  [fp32]; two staged passes.
__global__ __launch_bounds__(512) void post_final_kernel(
        const float* __restrict__ agg, const float* __restrict__ cnt,
        const float* __restrict__ xp, const float* __restrict__ Wl,
        const float* __restrict__ Wr, const float* __restrict__ bias,
        float* __restrict__ out, int N) {
    __shared__ unsigned int Bp[128 * 64];
    __shared__ __align__(16) float At[8][512];
    int wave = threadIdx.x >> 6, lane = threadIdx.x & 63;
    int base = (blockIdx.x * 8 + wave) * 4;
    float acc[4][2] = {{0.f,0.f},{0.f,0.f},{0.f,0.f},{0.f,0.f}};
    // pass 1: mean(agg) @ Wl
    stage_B(Wl, Bp, threadIdx.x);
    __syncthreads();
    load_rows(agg, cnt, 1.0f, base, N, lane, At[wave]);
    kloop_acc(At[wave], Bp, lane, acc);
    __syncthreads();               // all waves done reading Bp(Wl)
    // pass 2: xp @ Wr
    stage_B(Wr, Bp, threadIdx.x);
    __syncthreads();
    load_rows(xp, nullptr, 1.0f, base, N, lane, At[wave]);
    kloop_acc(At[wave], Bp, lane, acc);
    float b0 = bias[lane], b1 = bias[lane + 64];
#pragma unroll
    for (int i = 0; i < 4; ++i) {
        int row = base + i;
        if (row < N) {
            out[(size_t)row * DD + lane]      = fmaxf(acc[i][0] + b0, 0.f);
            out[(size_t)row * DD + lane + 64] = fmaxf(acc[i][1] + b1, 0.f);
        }
    }
}

// ------------------------------------------------------------------ launch --
extern "C" void kernel_launch(void* const* d_in, const int* in_sizes, int n_in,
                              void* d_out, int out_size, void* d_ws, size_t ws_size,
                              hipStream_t stream) {
    const float* x_user  = (const float*)d_in[0];
    const float* x_post  = (const float*)d_in[1];
    const int*   re_src  = (const int*)d_in[2];
    const int*   re_dst  = (const int*)d_in[3];
    const int*   fb_src  = (const int*)d_in[4];
    const int*   fb_dst  = (const int*)d_in[5];
    const int*   soc_src = (const int*)d_in[6];
    const int*   soc_dst = (const int*)d_in[7];
    const int*   eng_src = (const int*)d_in[8];
    const int*   eng_dst = (const int*)d_in[9];
    const float* Wl_d = (const float*)d_in[10];
    const float* bl_d = (const float*)d_in[11];
    const float* Wr_d = (const float*)d_in[12];
    const float* Wl_a = (const float*)d_in[13];
    const float* bl_a = (const float*)d_in[14];
    const float* Wr_a = (const float*)d_in[15];
    const float* Wl_s = (const float*)d_in[16];
    const float* bl_s = (const float*)d_in[17];
    const float* Wr_s = (const float*)d_in[18];
    const float* Wl_p = (const float*)d_in[19];
    const float* bl_p = (const float*)d_in[20];
    const float* Wr_p = (const float*)d_in[21];

    const int E_re  = in_sizes[2];
    const int E_fb  = in_sizes[4];
    const int E_soc = in_sizes[6];
    const int E_eng = in_sizes[8];

    float* ws   = (float*)d_ws;
    float* aggU = ws;                                   // 12.8M floats
    float* uacc = ws + (size_t)N_USER * DD;             // 12.8M floats
    float* aggP = ws;                                   // 25.6M floats (post phase)
    float* cntU = ws + (size_t)N_POST * DD;             // 100K floats
    float* cntP = cntU + N_USER;                        // 200K floats

    float* out_user = (float*)d_out;
    float* out_post = out_user + (size_t)N_USER * DD;

    const size_t aggU_bytes = (size_t)N_USER * DD * sizeof(float);
    const size_t aggP_bytes = (size_t)N_POST * DD * sizeof(float);

    const int SC_BLOCKS = 4096;
    const int gU = (N_USER + 31) / 32;   // 3125 blocks * 32 rows
    const int gP = (N_POST + 31) / 32;   // 6250 blocks * 32 rows

    // ---- user: direct (re: post -> user) ----
    hipMemsetAsync(aggU, 0, aggU_bytes, stream);
    hipMemsetAsync(uacc, 0, aggU_bytes, stream);
    hipMemsetAsync(cntU, 0, N_USER * sizeof(float), stream);
    scatter_add_kernel<<<SC_BLOCKS, 256, 0, stream>>>(x_post, re_src, re_dst, E_re, aggU, cntU);
    row_gemm_acc<<<gU, 512, 0, stream>>>(aggU, cntU, Wl_d, 1.75f, uacc, N_USER);

    // ---- user: author (fb: post -> user) ----
    hipMemsetAsync(aggU, 0, aggU_bytes, stream);
    hipMemsetAsync(cntU, 0, N_USER * sizeof(float), stream);
    scatter_add_kernel<<<SC_BLOCKS, 256, 0, stream>>>(x_post, fb_src, fb_dst, E_fb, aggU, cntU);
    row_gemm_acc<<<gU, 512, 0, stream>>>(aggU, cntU, Wl_a, 0.7f, uacc, N_USER);

    // ---- user: social (soc: user -> user) ----
    hipMemsetAsync(aggU, 0, aggU_bytes, stream);
    hipMemsetAsync(cntU, 0, N_USER * sizeof(float), stream);
    scatter_add_kernel<<<SC_BLOCKS, 256, 0, stream>>>(x_user, soc_src, soc_dst, E_soc, aggU, cntU);
    row_gemm_acc<<<gU, 512, 0, stream>>>(aggU, cntU, Wl_s, 0.3f, uacc, N_USER);

    // ---- user output ----
    user_final_kernel<<<gU, 512, 0, stream>>>(uacc, x_user, Wr_d, Wr_a, Wr_s,
                                              bl_d, bl_a, bl_s, out_user, N_USER);

    // ---- post: eng (user -> post) ----
    hipMemsetAsync(aggP, 0, aggP_bytes, stream);
    hipMemsetAsync(cntP, 0, N_POST * sizeof(float), stream);
    scatter_add_kernel<<<SC_BLOCKS, 256, 0, stream>>>(x_user, eng_src, eng_dst, E_eng, aggP, cntP);
    post_final_kernel<<<gP, 512, 0, stream>>>(aggP, cntP, x_post, Wl_p, Wr_p, bl_p,
                                              out_post, N_POST);
}

// Round 9
// 5457.080 us; speedup vs baseline: 6.2076x; 6.2076x over previous
//
#include <hip/hip_runtime.h>

// WeightedRGCN on MI355X. Round 9: identical to rounds 6-8 source (three
// consecutive UnresponsiveContainer infra failures on pod dual-thick-firm-lion;
// this code has never run). Fix under test: #pragma unroll 4 in the GEMM
// k-loop to kill the register spill R5's counters showed (post_final 18.2ms,
// 35GB scratch traffic, VALUBusy 1.5%, occupancy 24%).
//
// ws layout (floats), total 25.9M floats = 103.6 MB:
//   user phase: [0 .. 12.8M) aggU   [12.8M .. 25.6M) uacc
//   post phase: [0 .. 25.6M) aggP   (reuses both, after user_final)
//   [25.6M .. +100K) cntU   [25.7M .. +200K) cntP

#define N_USER 100000
#define N_POST 200000
#define DD 128

__device__ __forceinline__ unsigned int pack2_bf16(float lo, float hi) {
    unsigned int ulo, uhi;
    __builtin_memcpy(&ulo, &lo, 4);
    __builtin_memcpy(&uhi, &hi, 4);
    unsigned int rlo = (ulo + 0x7fffu + ((ulo >> 16) & 1u)) >> 16;   // RNE
    unsigned int rhi = (uhi + 0x7fffu + ((uhi >> 16) & 1u)) >> 16;
    return (rlo & 0xffffu) | (rhi << 16);
}
__device__ __forceinline__ float bf16_lo(unsigned int u) {
    unsigned int t = u << 16; float f; __builtin_memcpy(&f, &t, 4); return f;
}
__device__ __forceinline__ float bf16_hi(unsigned int u) {
    unsigned int t = u & 0xffff0000u; float f; __builtin_memcpy(&f, &t, 4); return f;
}

// ---------------------------------------------------------------- scatter ---
// One wave per edge (grid-stride). 512B coalesced fp32 gather, 128 atomics.
__global__ __launch_bounds__(256) void scatter_add_kernel(
        const float* __restrict__ xsrc, const int* __restrict__ src,
        const int* __restrict__ dst, int E,
        float* __restrict__ agg, float* __restrict__ cnt) {
    int lane = threadIdx.x & 63;
    int wave = (blockIdx.x * blockDim.x + threadIdx.x) >> 6;
    int nwaves = (gridDim.x * blockDim.x) >> 6;
    for (int e = wave; e < E; e += nwaves) {
        int s = src[e];
        int d = dst[e];
        float2 v = *reinterpret_cast<const float2*>(xsrc + (size_t)s * DD + lane * 2);
        float* ap = agg + (size_t)d * DD + lane * 2;
        atomicAdd(ap,     v.x);
        atomicAdd(ap + 1, v.y);
        if (lane == 0) atomicAdd(cnt + d, 1.0f);
    }
}

// ------------------------------------------------------------ GEMM pieces ---
// B (fp32 [128][128]) staged in LDS as bf16 column-pairs:
// Bp[k*64+j] = (bf16(B[k][j]), bf16(B[k][j+64])).
__device__ __forceinline__ void stage_B(const float* __restrict__ B,
                                        unsigned int* Bp, int tid) {
    for (int i = tid; i < 128 * 64; i += 512) {
        int k = i >> 6, j = i & 63;
        Bp[i] = pack2_bf16(B[k * 128 + j], B[k * 128 + j + 64]);
    }
}

// 4 rows of A (optionally mean-scaled) -> per-wave transposed LDS:
// at[k*4+i] = A[row_i][k] * inv_i  (k-loop broadcast = 1 ds_read_b128)
__device__ __forceinline__ void load_rows(const float* __restrict__ A,
                                          const float* __restrict__ cnt, float scale,
                                          int base, int N, int lane, float* at) {
#pragma unroll
    for (int i = 0; i < 4; ++i) {
        int row = base + i;
        float a0 = 0.f, a1 = 0.f;
        if (row < N) {
            float inv = scale;
            if (cnt) inv = scale / fmaxf(cnt[row], 1.0f);
            a0 = A[(size_t)row * DD + lane] * inv;
            a1 = A[(size_t)row * DD + 64 + lane] * inv;
        }
        at[lane * 4 + i] = a0;
        at[(lane + 64) * 4 + i] = a1;
    }
}

// acc[i][0] += A[row_i][:] . B[:][lane]; acc[i][1] += ... B[:][lane+64]
// unroll 4 (NOT full): full unroll spilled to scratch under the 128-VGPR cap
// (R5: 35GB of scratch traffic in post_final_kernel).
__device__ __forceinline__ void kloop_acc(const float* at, const unsigned int* Bp,
                                          int lane, float acc[4][2]) {
#pragma unroll 4
    for (int k = 0; k < 128; ++k) {
        float4 x = *reinterpret_cast<const float4*>(at + k * 4);
        unsigned int u = Bp[k * 64 + lane];
        float b0 = bf16_lo(u), b1 = bf16_hi(u);
        acc[0][0] = fmaf(x.x, b0, acc[0][0]); acc[0][1] = fmaf(x.x, b1, acc[0][1]);
        acc[1][0] = fmaf(x.y, b0, acc[1][0]); acc[1][1] = fmaf(x.y, b1, acc[1][1]);
        acc[2][0] = fmaf(x.z, b0, acc[2][0]); acc[2][1] = fmaf(x.z, b1, acc[2][1]);
        acc[3][0] = fmaf(x.w, b0, acc[3][0]); acc[3][1] = fmaf(x.w, b1, acc[3][1]);
    }
}

// Y (fp32) += scale * mean(A) @ B   (each row owned by exactly one wave)
__global__ __launch_bounds__(512) void row_gemm_acc(
        const float* __restrict__ A, const float* __restrict__ cnt,
        const float* __restrict__ B, float scale, float* __restrict__ Y, int N) {
    __shared__ unsigned int Bp[128 * 64];
    __shared__ __align__(16) float At[8][512];
    stage_B(B, Bp, threadIdx.x);
    __syncthreads();
    int wave = threadIdx.x >> 6, lane = threadIdx.x & 63;
    int base = (blockIdx.x * 8 + wave) * 4;
    float acc[4][2] = {{0.f,0.f},{0.f,0.f},{0.f,0.f},{0.f,0.f}};
    load_rows(A, cnt, scale, base, N, lane, At[wave]);
    kloop_acc(At[wave], Bp, lane, acc);
#pragma unroll
    for (int i = 0; i < 4; ++i) {
        int row = base + i;
        if (row < N) {
            float* y = Y + (size_t)row * DD + lane;
            y[0]  += acc[i][0];
            y[64] += acc[i][1];
        }
    }
}

// out_user = relu(uacc + xU @ (1.75 WrD + 0.7 WrA + 0.3 WrS) + b_comb) [fp32]
__global__ __launch_bounds__(512) void user_final_kernel(
        const float* __restrict__ uacc, const float* __restrict__ xu,
        const float* __restrict__ WrD, const float* __restrict__ WrA,
        const float* __restrict__ WrS, const float* __restrict__ bD,
        const float* __restrict__ bA, const float* __restrict__ bS,
        float* __restrict__ out, int N) {
    __shared__ unsigned int Bp[128 * 64];
    __shared__ __align__(16) float At[8][512];
    for (int i = threadIdx.x; i < 128 * 64; i += 512) {
        int k = i >> 6, j = i & 63;
        float lo = 1.75f * WrD[k*128+j]    + 0.7f * WrA[k*128+j]    + 0.3f * WrS[k*128+j];
        float hi = 1.75f * WrD[k*128+j+64] + 0.7f * WrA[k*128+j+64] + 0.3f * WrS[k*128+j+64];
        Bp[i] = pack2_bf16(lo, hi);
    }
    __syncthreads();
    int wave = threadIdx.x >> 6, lane = threadIdx.x & 63;
    int base = (blockIdx.x * 8 + wave) * 4;
    float acc[4][2] = {{0.f,0.f},{0.f,0.f},{0.f,0.f},{0.f,0.f}};
    load_rows(xu, nullptr, 1.0f, base, N, lane, At[wave]);
    kloop_acc(At[wave], Bp, lane, acc);
    float bc0 = 1.75f*bD[lane]    + 0.7f*bA[lane]    + 0.3f*bS[lane];
    float bc1 = 1.75f*bD[lane+64] + 0.7f*bA[lane+64] + 0.3f*bS[lane+64];
#pragma unroll
    for (int i = 0; i < 4; ++i) {
        int row = base + i;
        if (row < N) {
            const float* u = uacc + (size_t)row * DD + lane;
            out[(size_t)row * DD + lane]      = fmaxf(u[0]  + acc[i][0] + bc0, 0.f);
            out[(size_t)row * DD + lane + 64] = fmaxf(u[64] + acc[i][1] + bc1, 0.f);
        }
    }
}

// out_post = relu(mean(aggP) @ Wl + xP @ Wr + b)  [fp32]; two staged passes.
__global__ __launch_bounds__(512) void post_final_kernel(
        const float* __restrict__ agg, const float* __restrict__ cnt,
        const float* __restrict__ xp, const float* __restrict__ Wl,
        const float* __restrict__ Wr, const float* __restrict__ bias,
        float* __restrict__ out, int N) {
    __shared__ unsigned int Bp[128 * 64];
    __shared__ __align__(16) float At[8][512];
    int wave = threadIdx.x >> 6, lane = threadIdx.x & 63;
    int base = (blockIdx.x * 8 + wave) * 4;
    float acc[4][2] = {{0.f,0.f},{0.f,0.f},{0.f,0.f},{0.f,0.f}};
    // pass 1: mean(agg) @ Wl
    stage_B(Wl, Bp, threadIdx.x);
    __syncthreads();
    load_rows(agg, cnt, 1.0f, base, N, lane, At[wave]);
    kloop_acc(At[wave], Bp, lane, acc);
    __syncthreads();               // all waves done reading Bp(Wl)
    // pass 2: xp @ Wr
    stage_B(Wr, Bp, threadIdx.x);
    __syncthreads();
    load_rows(xp, nullptr, 1.0f, base, N, lane, At[wave]);
    kloop_acc(At[wave], Bp, lane, acc);
    float b0 = bias[lane], b1 = bias[lane + 64];
#pragma unroll
    for (int i = 0; i < 4; ++i) {
        int row = base + i;
        if (row < N) {
            out[(size_t)row * DD + lane]      = fmaxf(acc[i][0] + b0, 0.f);
            out[(size_t)row * DD + lane + 64] = fmaxf(acc[i][1] + b1, 0.f);
        }
    }
}

// ------------------------------------------------------------------ launch --
extern "C" void kernel_launch(void* const* d_in, const int* in_sizes, int n_in,
                              void* d_out, int out_size, void* d_ws, size_t ws_size,
                              hipStream_t stream) {
    const float* x_user  = (const float*)d_in[0];
    const float* x_post  = (const float*)d_in[1];
    const int*   re_src  = (const int*)d_in[2];
    const int*   re_dst  = (const int*)d_in[3];
    const int*   fb_src  = (const int*)d_in[4];
    const int*   fb_dst  = (const int*)d_in[5];
    const int*   soc_src = (const int*)d_in[6];
    const int*   soc_dst = (const int*)d_in[7];
    const int*   eng_src = (const int*)d_in[8];
    const int*   eng_dst = (const int*)d_in[9];
    const float* Wl_d = (const float*)d_in[10];
    const float* bl_d = (const float*)d_in[11];
    const float* Wr_d = (const float*)d_in[12];
    const float* Wl_a = (const float*)d_in[13];
    const float* bl_a = (const float*)d_in[14];
    const float* Wr_a = (const float*)d_in[15];
    const float* Wl_s = (const float*)d_in[16];
    const float* bl_s = (const float*)d_in[17];
    const float* Wr_s = (const float*)d_in[18];
    const float* Wl_p = (const float*)d_in[19];
    const float* bl_p = (const float*)d_in[20];
    const float* Wr_p = (const float*)d_in[21];

    const int E_re  = in_sizes[2];
    const int E_fb  = in_sizes[4];
    const int E_soc = in_sizes[6];
    const int E_eng = in_sizes[8];

    float* ws   = (float*)d_ws;
    float* aggU = ws;                                   // 12.8M floats
    float* uacc = ws + (size_t)N_USER * DD;             // 12.8M floats
    float* aggP = ws;                                   // 25.6M floats (post phase)
    float* cntU = ws + (size_t)N_POST * DD;             // 100K floats
    float* cntP = cntU + N_USER;                        // 200K floats

    float* out_user = (float*)d_out;
    float* out_post = out_user + (size_t)N_USER * DD;

    const size_t aggU_bytes = (size_t)N_USER * DD * sizeof(float);
    const size_t aggP_bytes = (size_t)N_POST * DD * sizeof(float);

    const int SC_BLOCKS = 4096;
    const int gU = (N_USER + 31) / 32;   // 3125 blocks * 32 rows
    const int gP = (N_POST + 31) / 32;   // 6250 blocks * 32 rows

    // ---- user: direct (re: post -> user) ----
    hipMemsetAsync(aggU, 0, aggU_bytes, stream);
    hipMemsetAsync(uacc, 0, aggU_bytes, stream);
    hipMemsetAsync(cntU, 0, N_USER * sizeof(float), stream);
    scatter_add_kernel<<<SC_BLOCKS, 256, 0, stream>>>(x_post, re_src, re_dst, E_re, aggU, cntU);
    row_gemm_acc<<<gU, 512, 0, stream>>>(aggU, cntU, Wl_d, 1.75f, uacc, N_USER);

    // ---- user: author (fb: post -> user) ----
    hipMemsetAsync(aggU, 0, aggU_bytes, stream);
    hipMemsetAsync(cntU, 0, N_USER * sizeof(float), stream);
    scatter_add_kernel<<<SC_BLOCKS, 256, 0, stream>>>(x_post, fb_src, fb_dst, E_fb, aggU, cntU);
    row_gemm_acc<<<gU, 512, 0, stream>>>(aggU, cntU, Wl_a, 0.7f, uacc, N_USER);

    // ---- user: social (soc: user -> user) ----
    hipMemsetAsync(aggU, 0, aggU_bytes, stream);
    hipMemsetAsync(cntU, 0, N_USER * sizeof(float), stream);
    scatter_add_kernel<<<SC_BLOCKS, 256, 0, stream>>>(x_user, soc_src, soc_dst, E_soc, aggU, cntU);
    row_gemm_acc<<<gU, 512, 0, stream>>>(aggU, cntU, Wl_s, 0.3f, uacc, N_USER);

    // ---- user output ----
    user_final_kernel<<<gU, 512, 0, stream>>>(uacc, x_user, Wr_d, Wr_a, Wr_s,
                                              bl_d, bl_a, bl_s, out_user, N_USER);

    // ---- post: eng (user -> post) ----
    hipMemsetAsync(aggP, 0, aggP_bytes, stream);
    hipMemsetAsync(cntP, 0, N_POST * sizeof(float), stream);
    scatter_add_kernel<<<SC_BLOCKS, 256, 0, stream>>>(x_user, eng_src, eng_dst, E_eng, aggP, cntP);
    post_final_kernel<<<gP, 512, 0, stream>>>(aggP, cntP, x_post, Wl_p, Wr_p, bl_p,
                                              out_post, N_POST);
}

// Round 10
// 2274.402 us; speedup vs baseline: 14.8941x; 2.3993x over previous
//
#include <hip/hip_runtime.h>

// WeightedRGCN on MI355X. Round 10: replace atomic-scatter aggregation with
// on-device CSR build + pull-mode aggregation fused into the GEMM kernels.
// R9 counters: 4 scatter kernels = 4.8ms of 5.46ms, WRITE_SIZE 1.65GB per
// dispatch (32x the 51MB agg buffer) -> fp32-atomic write amplification.
// Pull mode: zero fp atomics; writes shrink to uacc(51MB)+outputs.
//
// ws layout (words), total ~14.8M = 59.2 MB:
//   [0 .. 12.8M)           uacc (fp32 user accumulator)
//   [12.8M .. +1.6M)       col_idx (int)
//   [14.4M .. +200001)     row_ptr (int)
//   [14.600001M .. +200K)  wcur (int fill cursors)

#define N_USER 100000
#define N_POST 200000
#define DD 128
#define E_MAX 1600000

__device__ __forceinline__ unsigned int pack2_bf16(float lo, float hi) {
    unsigned int ulo, uhi;
    __builtin_memcpy(&ulo, &lo, 4);
    __builtin_memcpy(&uhi, &hi, 4);
    unsigned int rlo = (ulo + 0x7fffu + ((ulo >> 16) & 1u)) >> 16;   // RNE
    unsigned int rhi = (uhi + 0x7fffu + ((uhi >> 16) & 1u)) >> 16;
    return (rlo & 0xffffu) | (rhi << 16);
}
__device__ __forceinline__ float bf16_lo(unsigned int u) {
    unsigned int t = u << 16; float f; __builtin_memcpy(&f, &t, 4); return f;
}
__device__ __forceinline__ float bf16_hi(unsigned int u) {
    unsigned int t = u & 0xffff0000u; float f; __builtin_memcpy(&f, &t, 4); return f;
}

// -------------------------------------------------------------- CSR build ---
__global__ __launch_bounds__(256) void csr_hist(
        const int* __restrict__ dst, int E, int* __restrict__ cnt) {
    int i = blockIdx.x * 256 + threadIdx.x;
    int stride = gridDim.x * 256;
    for (int e = i; e < E; e += stride) atomicAdd(&cnt[dst[e]], 1);
}

// single-block exclusive scan, in-place: a[0..N) counts -> a[0..N] offsets.
#define SCAN_T 1024
#define SCAN_EPT 8
__global__ __launch_bounds__(SCAN_T) void scan_excl(int* __restrict__ a, int N) {
    __shared__ int tsum[SCAN_T];
    __shared__ int carry_s;
    int tid = threadIdx.x;
    if (tid == 0) carry_s = 0;
    __syncthreads();
    const int CH = SCAN_T * SCAN_EPT;
    for (int base = 0; base < N; base += CH) {
        int v[SCAN_EPT];
        int mysum = 0;
        int i0 = base + tid * SCAN_EPT;
#pragma unroll
        for (int j = 0; j < SCAN_EPT; ++j) {
            int i = i0 + j;
            v[j] = (i < N) ? a[i] : 0;
            mysum += v[j];
        }
        tsum[tid] = mysum;
        __syncthreads();
        for (int off = 1; off < SCAN_T; off <<= 1) {
            int t = (tid >= off) ? tsum[tid - off] : 0;
            __syncthreads();
            tsum[tid] += t;
            __syncthreads();
        }
        int carry = carry_s;
        int run = carry + tsum[tid] - mysum;   // exclusive prefix of this thread
#pragma unroll
        for (int j = 0; j < SCAN_EPT; ++j) {
            int i = i0 + j;
            if (i < N) a[i] = run;
            run += v[j];
        }
        __syncthreads();
        if (tid == SCAN_T - 1) carry_s = carry + tsum[tid];
        __syncthreads();
    }
    if (tid == 0) a[N] = carry_s;
}

__global__ __launch_bounds__(256) void csr_fill(
        const int* __restrict__ src, const int* __restrict__ dst, int E,
        const int* __restrict__ rp, int* __restrict__ wcur, int* __restrict__ col) {
    int i = blockIdx.x * 256 + threadIdx.x;
    int stride = gridDim.x * 256;
    for (int e = i; e < E; e += stride) {
        int d = dst[e];
        int pos = rp[d] + atomicAdd(&wcur[d], 1);
        col[pos] = src[e];
    }
}

// ------------------------------------------------------------ GEMM pieces ---
// B (fp32 [128][128]) staged in LDS as bf16 column-pairs:
// Bp[k*64+j] = (bf16(B[k][j]), bf16(B[k][j+64])).
__device__ __forceinline__ void stage_B(const float* __restrict__ B,
                                        unsigned int* Bp, int tid) {
    for (int i = tid; i < 128 * 64; i += 512) {
        int k = i >> 6, j = i & 63;
        Bp[i] = pack2_bf16(B[k * 128 + j], B[k * 128 + j + 64]);
    }
}

// 4 dense rows -> per-wave transposed LDS: at[k*4+i] = A[row_i][k]
__device__ __forceinline__ void load_rows(const float* __restrict__ A,
                                          int base, int N, int lane, float* at) {
#pragma unroll
    for (int i = 0; i < 4; ++i) {
        int row = base + i;
        float a0 = 0.f, a1 = 0.f;
        if (row < N) {
            a0 = A[(size_t)row * DD + lane];
            a1 = A[(size_t)row * DD + 64 + lane];
        }
        at[lane * 4 + i] = a0;
        at[(lane + 64) * 4 + i] = a1;
    }
}

// 4 CSR-mean rows -> per-wave transposed LDS:
// at[k*4+i] = scale/deg * sum_{e in row_i} x[col[e]][k]
__device__ __forceinline__ void gather_rows(const float* __restrict__ x,
                                            const int* __restrict__ rp,
                                            const int* __restrict__ col, float scale,
                                            int base, int N, int lane, float* at) {
#pragma unroll
    for (int i = 0; i < 4; ++i) {
        int row = base + i;
        float a0 = 0.f, a1 = 0.f;
        if (row < N) {
            int s0 = rp[row], s1 = rp[row + 1];
            for (int e = s0; e < s1; ++e) {
                const float* xr = x + (size_t)col[e] * DD;
                a0 += xr[lane];
                a1 += xr[lane + 64];
            }
            float inv = scale / fmaxf((float)(s1 - s0), 1.0f);
            a0 *= inv;
            a1 *= inv;
        }
        at[lane * 4 + i] = a0;
        at[(lane + 64) * 4 + i] = a1;
    }
}

// acc[i][0] += A[row_i][:] . B[:][lane]; acc[i][1] += ... B[:][lane+64]
// unroll 4 (NOT full): full unroll spills under the 128-VGPR cap (R5 35GB).
__device__ __forceinline__ void kloop_acc(const float* at, const unsigned int* Bp,
                                          int lane, float acc[4][2]) {
#pragma unroll 4
    for (int k = 0; k < 128; ++k) {
        float4 x = *reinterpret_cast<const float4*>(at + k * 4);
        unsigned int u = Bp[k * 64 + lane];
        float b0 = bf16_lo(u), b1 = bf16_hi(u);
        acc[0][0] = fmaf(x.x, b0, acc[0][0]); acc[0][1] = fmaf(x.x, b1, acc[0][1]);
        acc[1][0] = fmaf(x.y, b0, acc[1][0]); acc[1][1] = fmaf(x.y, b1, acc[1][1]);
        acc[2][0] = fmaf(x.z, b0, acc[2][0]); acc[2][1] = fmaf(x.z, b1, acc[2][1]);
        acc[3][0] = fmaf(x.w, b0, acc[3][0]); acc[3][1] = fmaf(x.w, b1, acc[3][1]);
    }
}

// Y += scale * csr_mean(x) @ B   (pull aggregation fused with GEMM)
__global__ __launch_bounds__(512) void pull_gemm_acc(
        const float* __restrict__ x, const int* __restrict__ rp,
        const int* __restrict__ col, const float* __restrict__ B,
        float scale, float* __restrict__ Y, int N) {
    __shared__ unsigned int Bp[128 * 64];
    __shared__ __align__(16) float At[8][512];
    stage_B(B, Bp, threadIdx.x);
    __syncthreads();
    int wave = threadIdx.x >> 6, lane = threadIdx.x & 63;
    int base = (blockIdx.x * 8 + wave) * 4;
    float acc[4][2] = {{0.f,0.f},{0.f,0.f},{0.f,0.f},{0.f,0.f}};
    gather_rows(x, rp, col, scale, base, N, lane, At[wave]);
    kloop_acc(At[wave], Bp, lane, acc);
#pragma unroll
    for (int i = 0; i < 4; ++i) {
        int row = base + i;
        if (row < N) {
            float* y = Y + (size_t)row * DD + lane;
            y[0]  += acc[i][0];
            y[64] += acc[i][1];
        }
    }
}

// out_user = relu(uacc + xU @ (1.75 WrD + 0.7 WrA + 0.3 WrS) + b_comb) [fp32]
__global__ __launch_bounds__(512) void user_final_kernel(
        const float* __restrict__ uacc, const float* __restrict__ xu,
        const float* __restrict__ WrD, const float* __restrict__ WrA,
        const float* __restrict__ WrS, const float* __restrict__ bD,
        const float* __restrict__ bA, const float* __restrict__ bS,
        float* __restrict__ out, int N) {
    __shared__ unsigned int Bp[128 * 64];
    __shared__ __align__(16) float At[8][512];
    for (int i = threadIdx.x; i < 128 * 64; i += 512) {
        int k = i >> 6, j = i & 63;
        float lo = 1.75f * WrD[k*128+j]    + 0.7f * WrA[k*128+j]    + 0.3f * WrS[k*128+j];
        float hi = 1.75f * WrD[k*128+j+64] + 0.7f * WrA[k*128+j+64] + 0.3f * WrS[k*128+j+64];
        Bp[i] = pack2_bf16(lo, hi);
    }
    __syncthreads();
    int wave = threadIdx.x >> 6, lane = threadIdx.x & 63;
    int base = (blockIdx.x * 8 + wave) * 4;
    float acc[4][2] = {{0.f,0.f},{0.f,0.f},{0.f,0.f},{0.f,0.f}};
    load_rows(xu, base, N, lane, At[wave]);
    kloop_acc(At[wave], Bp, lane, acc);
    float bc0 = 1.75f*bD[lane]    + 0.7f*bA[lane]    + 0.3f*bS[lane];
    float bc1 = 1.75f*bD[lane+64] + 0.7f*bA[lane+64] + 0.3f*bS[lane+64];
#pragma unroll
    for (int i = 0; i < 4; ++i) {
        int row = base + i;
        if (row < N) {
            const float* u = uacc + (size_t)row * DD + lane;
            out[(size_t)row * DD + lane]      = fmaxf(u[0]  + acc[i][0] + bc0, 0.f);
            out[(size_t)row * DD + lane + 64] = fmaxf(u[64] + acc[i][1] + bc1, 0.f);
        }
    }
}

// out_post = relu(csr_mean(xu) @ Wl + xP @ Wr + b)  [fp32]; two staged passes.
__global__ __launch_bounds__(512) void post_final_kernel(
        const float* __restrict__ xu, const int* __restrict__ rp,
        const int* __restrict__ col, const float* __restrict__ xp,
        const float* __restrict__ Wl, const float* __restrict__ Wr,
        const float* __restrict__ bias, float* __restrict__ out, int N) {
    __shared__ unsigned int Bp[128 * 64];
    __shared__ __align__(16) float At[8][512];
    int wave = threadIdx.x >> 6, lane = threadIdx.x & 63;
    int base = (blockIdx.x * 8 + wave) * 4;
    float acc[4][2] = {{0.f,0.f},{0.f,0.f},{0.f,0.f},{0.f,0.f}};
    // pass 1: csr_mean(xu) @ Wl
    stage_B(Wl, Bp, threadIdx.x);
    __syncthreads();
    gather_rows(xu, rp, col, 1.0f, base, N, lane, At[wave]);
    kloop_acc(At[wave], Bp, lane, acc);
    __syncthreads();               // all waves done reading Bp(Wl)
    // pass 2: xp @ Wr
    stage_B(Wr, Bp, threadIdx.x);
    __syncthreads();
    load_rows(xp, base, N, lane, At[wave]);
    kloop_acc(At[wave], Bp, lane, acc);
    float b0 = bias[lane], b1 = bias[lane + 64];
#pragma unroll
    for (int i = 0; i < 4; ++i) {
        int row = base + i;
        if (row < N) {
            out[(size_t)row * DD + lane]      = fmaxf(acc[i][0] + b0, 0.f);
            out[(size_t)row * DD + lane + 64] = fmaxf(acc[i][1] + b1, 0.f);
        }
    }
}

// ------------------------------------------------------------------ launch --
extern "C" void kernel_launch(void* const* d_in, const int* in_sizes, int n_in,
                              void* d_out, int out_size, void* d_ws, size_t ws_size,
                              hipStream_t stream) {
    const float* x_user  = (const float*)d_in[0];
    const float* x_post  = (const float*)d_in[1];
    const int*   re_src  = (const int*)d_in[2];
    const int*   re_dst  = (const int*)d_in[3];
    const int*   fb_src  = (const int*)d_in[4];
    const int*   fb_dst  = (const int*)d_in[5];
    const int*   soc_src = (const int*)d_in[6];
    const int*   soc_dst = (const int*)d_in[7];
    const int*   eng_src = (const int*)d_in[8];
    const int*   eng_dst = (const int*)d_in[9];
    const float* Wl_d = (const float*)d_in[10];
    const float* bl_d = (const float*)d_in[11];
    const float* Wr_d = (const float*)d_in[12];
    const float* Wl_a = (const float*)d_in[13];
    const float* bl_a = (const float*)d_in[14];
    const float* Wr_a = (const float*)d_in[15];
    const float* Wl_s = (const float*)d_in[16];
    const float* bl_s = (const float*)d_in[17];
    const float* Wr_s = (const float*)d_in[18];
    const float* Wl_p = (const float*)d_in[19];
    const float* bl_p = (const float*)d_in[20];
    const float* Wr_p = (const float*)d_in[21];

    const int E_re  = in_sizes[2];
    const int E_fb  = in_sizes[4];
    const int E_soc = in_sizes[6];
    const int E_eng = in_sizes[8];

    float* uacc    = (float*)d_ws;                               // 12.8M floats
    int*   col_idx = (int*)((float*)d_ws + (size_t)N_USER * DD); // 1.6M ints
    int*   row_ptr = col_idx + E_MAX;                            // 200001 ints
    int*   wcur    = row_ptr + (N_POST + 1);                     // 200000 ints

    float* out_user = (float*)d_out;
    float* out_post = out_user + (size_t)N_USER * DD;

    const int gU = (N_USER + 31) / 32;   // 3125 blocks * 32 rows
    const int gP = (N_POST + 31) / 32;   // 6250 blocks * 32 rows

    // CSR build for one relation (dst-indexed), reusing the same buffers.
    auto build_csr = [&](const int* src, const int* dst, int E, int Ndst) {
        hipMemsetAsync(row_ptr, 0, (Ndst + 1) * sizeof(int), stream);
        hipMemsetAsync(wcur, 0, Ndst * sizeof(int), stream);
        csr_hist<<<1024, 256, 0, stream>>>(dst, E, row_ptr);
        scan_excl<<<1, SCAN_T, 0, stream>>>(row_ptr, Ndst);
        csr_fill<<<1024, 256, 0, stream>>>(src, dst, E, row_ptr, wcur, col_idx);
    };

    hipMemsetAsync(uacc, 0, (size_t)N_USER * DD * sizeof(float), stream);

    // ---- user: direct (re: post -> user) ----
    build_csr(re_src, re_dst, E_re, N_USER);
    pull_gemm_acc<<<gU, 512, 0, stream>>>(x_post, row_ptr, col_idx, Wl_d, 1.75f, uacc, N_USER);

    // ---- user: author (fb: post -> user) ----
    build_csr(fb_src, fb_dst, E_fb, N_USER);
    pull_gemm_acc<<<gU, 512, 0, stream>>>(x_post, row_ptr, col_idx, Wl_a, 0.7f, uacc, N_USER);

    // ---- user: social (soc: user -> user) ----
    build_csr(soc_src, soc_dst, E_soc, N_USER);
    pull_gemm_acc<<<gU, 512, 0, stream>>>(x_user, row_ptr, col_idx, Wl_s, 0.3f, uacc, N_USER);

    // ---- user output ----
    user_final_kernel<<<gU, 512, 0, stream>>>(uacc, x_user, Wr_d, Wr_a, Wr_s,
                                              bl_d, bl_a, bl_s, out_user, N_USER);

    // ---- post: eng (user -> post) ----
    build_csr(eng_src, eng_dst, E_eng, N_POST);
    post_final_kernel<<<gP, 512, 0, stream>>>(x_user, row_ptr, col_idx, x_post,
                                              Wl_p, Wr_p, bl_p, out_post, N_POST);
}